// Round 4
// baseline (2152.144 us; speedup 1.0000x reference)
//
#include <hip/hip_runtime.h>
#include <hip/hip_bf16.h>
#include <stdint.h>

typedef unsigned short ushort_t;
typedef short bf16x8_t __attribute__((ext_vector_type(8)));   // 8 bf16 as shorts (guide §3)
typedef float f32x4_t __attribute__((ext_vector_type(4)));

#define IGNORE_INDEX (-100)

constexpr int B_ = 4, S_ = 2048, D_ = 2048, V_ = 32000;
constexpr int N_ = B_ * (S_ - 1);   // 8188 valid rows
constexpr int Npad = 8192;          // padded to 64 tiles of 128
constexpr int NVT = 500;            // 64-col partial tiles: 32000/64

#define TILE_M 128
#define TILE_N 128
#define TILE_K 64

__device__ inline unsigned short f2bf(float f) {
  unsigned int x = __float_as_uint(f);
  x += 0x7fffu + ((x >> 16) & 1u);   // round-to-nearest-even
  return (unsigned short)(x >> 16);
}
__device__ inline unsigned int pack2(float a, float b) {
  return (unsigned int)f2bf(a) | ((unsigned int)f2bf(b) << 16);
}

// ---- convert shifted hidden (fp32) -> bf16 [Npad][D], zero padding rows; zero accumulators ----
__global__ void conv_h_kernel(const float* __restrict__ h, ushort_t* __restrict__ hb,
                              float* __restrict__ accbuf) {
  if (blockIdx.x == 0 && threadIdx.x == 0) { accbuf[0] = 0.f; accbuf[1] = 0.f; }
  const int total = Npad * (D_ / 8);   // 8 elems per iter
  for (int q = blockIdx.x * blockDim.x + threadIdx.x; q < total; q += gridDim.x * blockDim.x) {
    const int n = q >> 8;             // D_/8 = 256
    const int c8 = q & 255;
    uint4 o;
    if (n < N_) {
      const int b = n / 2047;
      const int s = n - b * 2047;
      const float* src = h + (size_t)(b * S_ + s) * D_ + c8 * 8;
      const float4 a = *(const float4*)src;
      const float4 c = *(const float4*)(src + 4);
      o.x = pack2(a.x, a.y); o.y = pack2(a.z, a.w);
      o.z = pack2(c.x, c.y); o.w = pack2(c.z, c.w);
    } else {
      o.x = 0u; o.y = 0u; o.z = 0u; o.w = 0u;
    }
    *(uint4*)&hb[(size_t)n * D_ + c8 * 8] = o;
  }
}

// ---- convert lm_head weight (fp32) -> bf16 [V][D] ----
__global__ void conv_w_kernel(const float* __restrict__ w, ushort_t* __restrict__ wb) {
  const int total = V_ * (D_ / 8);     // 8,192,000
  for (int q = blockIdx.x * blockDim.x + threadIdx.x; q < total; q += gridDim.x * blockDim.x) {
    const float* src = w + (size_t)q * 8;
    const float4 a = *(const float4*)src;
    const float4 c = *(const float4*)(src + 4);
    uint4 o;
    o.x = pack2(a.x, a.y); o.y = pack2(a.z, a.w);
    o.z = pack2(c.x, c.y); o.w = pack2(c.z, c.w);
    *(uint4*)&wb[(size_t)q * 8] = o;
  }
}

// ---- label logit: z[n] = dot(h[n], W[label[n]]) in fp32 ----
__global__ __launch_bounds__(256) void zlabel_kernel(const float* __restrict__ h,
                                                     const float* __restrict__ wgt,
                                                     const int* __restrict__ labels,
                                                     float* __restrict__ zl) {
  __shared__ float red[4];
  const int n = blockIdx.x;
  const int b = n / 2047;
  const int s = n - b * 2047;
  const int t = labels[b * S_ + s + 1];
  float sum = 0.f;
  if (t >= 0 && t < V_) {
    const float4* hr = (const float4*)(h + (size_t)(b * S_ + s) * D_);
    const float4* wr = (const float4*)(wgt + (size_t)t * D_);
    #pragma unroll
    for (int i = 0; i < 2; ++i) {
      const int idx = threadIdx.x + i * 256;
      const float4 a = hr[idx];
      const float4 c = wr[idx];
      sum += a.x * c.x + a.y * c.y + a.z * c.z + a.w * c.w;
    }
  }
  #pragma unroll
  for (int d = 32; d >= 1; d >>= 1) sum += __shfl_down(sum, d, 64);
  const int w = threadIdx.x >> 6, l = threadIdx.x & 63;
  if (l == 0) red[w] = sum;
  __syncthreads();
  if (threadIdx.x == 0) zl[n] = red[0] + red[1] + red[2] + red[3];
}

// ---- main fused GEMM + partial (max, sum-exp) per row per 64-col tile ----
// m97 structure: 128x128 tile, BK=64, 4 waves (2x2), 16x16x32 bf16 MFMA, global_load_lds w=16.
__global__ __launch_bounds__(256) void gemm_lse_kernel(const ushort_t* __restrict__ hb,
                                                       const ushort_t* __restrict__ wb,
                                                       float* __restrict__ pmax,
                                                       float* __restrict__ psum) {
  __shared__ alignas(16) ushort_t Al[TILE_M * TILE_K];  // [128][64] bf16, 16KB
  __shared__ alignas(16) ushort_t Bl[TILE_N * TILE_K];  // [128][64] bf16, 16KB

  const int tid = threadIdx.x;
  const int w = tid >> 6;          // wave 0..3
  const int l = tid & 63;          // lane
  const int wr = w >> 1, wc = w & 1;
  const int mt = blockIdx.y, vt = blockIdx.x;
  const int m0 = mt * TILE_M, v0 = vt * TILE_N;

  const int srow = l >> 3;         // 0..7 row-within-chunk for staging
  const int scol = (l & 7) * 8;    // element col for staging (16B)

  f32x4_t acc[4][4];
  #pragma unroll
  for (int i = 0; i < 4; ++i)
    #pragma unroll
    for (int j = 0; j < 4; ++j)
      acc[i][j] = (f32x4_t){0.f, 0.f, 0.f, 0.f};

  const int lr = l & 15, lg = l >> 4;

  for (int k0 = 0; k0 < D_; k0 += TILE_K) {
    #pragma unroll
    for (int i = 0; i < 4; ++i) {
      const int c = i * 4 + w;                 // chunk 0..15 (1KB each)
      const int r = c * 8 + srow;              // tile row 0..127
      const ushort_t* ga = hb + (size_t)(m0 + r) * D_ + k0 + scol;
      const ushort_t* gb = wb + (size_t)(v0 + r) * D_ + k0 + scol;
      __builtin_amdgcn_global_load_lds(
          (__attribute__((address_space(1))) void*)const_cast<ushort_t*>(ga),
          (__attribute__((address_space(3))) void*)&Al[c * 512], 16, 0, 0);
      __builtin_amdgcn_global_load_lds(
          (__attribute__((address_space(1))) void*)const_cast<ushort_t*>(gb),
          (__attribute__((address_space(3))) void*)&Bl[c * 512], 16, 0, 0);
    }
    __syncthreads();
    #pragma unroll
    for (int kk = 0; kk < 2; ++kk) {
      bf16x8_t af[4], bfv[4];
      #pragma unroll
      for (int mi = 0; mi < 4; ++mi)
        af[mi] = *(const bf16x8_t*)&Al[(wr * 64 + mi * 16 + lr) * TILE_K + kk * 32 + lg * 8];
      #pragma unroll
      for (int ni = 0; ni < 4; ++ni)
        bfv[ni] = *(const bf16x8_t*)&Bl[(wc * 64 + ni * 16 + lr) * TILE_K + kk * 32 + lg * 8];
      #pragma unroll
      for (int mi = 0; mi < 4; ++mi)
        #pragma unroll
        for (int ni = 0; ni < 4; ++ni)
          acc[mi][ni] = __builtin_amdgcn_mfma_f32_16x16x32_bf16(af[mi], bfv[ni], acc[mi][ni], 0, 0, 0);
    }
    __syncthreads();
  }

  // Epilogue: per row (fixed mi, lg, r), lane holds 4 cols (ni*16 + lr).
  // Reduce across the 16 lanes sharing lg -> (max, sum-exp) over this wave's 64 cols.
  const int vt64 = vt * 2 + wc;
  #pragma unroll
  for (int mi = 0; mi < 4; ++mi) {
    #pragma unroll
    for (int r = 0; r < 4; ++r) {
      float mx = fmaxf(fmaxf(acc[mi][0][r], acc[mi][1][r]),
                       fmaxf(acc[mi][2][r], acc[mi][3][r]));
      #pragma unroll
      for (int d = 1; d < 16; d <<= 1) mx = fmaxf(mx, __shfl_xor(mx, d, 64));
      float s = 0.f;
      #pragma unroll
      for (int ni = 0; ni < 4; ++ni) s += __expf(acc[mi][ni][r] - mx);
      #pragma unroll
      for (int d = 1; d < 16; d <<= 1) s += __shfl_xor(s, d, 64);
      if (lr == 0) {
        const int grow = m0 + wr * 64 + mi * 16 + lg * 4 + r;
        pmax[(size_t)vt64 * Npad + grow] = mx;
        psum[(size_t)vt64 * Npad + grow] = s;
      }
    }
  }
}

// ---- per-row online logsumexp over 500 partials, NLL, block-reduce, atomic ----
__global__ __launch_bounds__(256) void finalize_kernel(const float* __restrict__ pmax,
                                                       const float* __restrict__ psum,
                                                       const float* __restrict__ zl,
                                                       const int* __restrict__ labels,
                                                       float* __restrict__ accbuf) {
  const int n = blockIdx.x * 256 + threadIdx.x;
  float nll = 0.f, cnt = 0.f;
  if (n < N_) {
    const int b = n / 2047;
    const int s = n - b * 2047;
    const int t = labels[b * S_ + s + 1];
    if (t != IGNORE_INDEX) {
      float m = -3.4e38f, sum = 0.f;
      for (int v = 0; v < NVT; ++v) {
        const float pm = pmax[(size_t)v * Npad + n];
        const float ps = psum[(size_t)v * Npad + n];
        const float nm = fmaxf(m, pm);
        sum = sum * __expf(m - nm) + ps * __expf(pm - nm);
        m = nm;
      }
      nll = m + __logf(sum) - zl[n];
      cnt = 1.f;
    }
  }
  float vs = nll, vc = cnt;
  #pragma unroll
  for (int d = 32; d >= 1; d >>= 1) { vs += __shfl_down(vs, d, 64); vc += __shfl_down(vc, d, 64); }
  __shared__ float rs[4], rc[4];
  const int w = threadIdx.x >> 6, l = threadIdx.x & 63;
  if (l == 0) { rs[w] = vs; rc[w] = vc; }
  __syncthreads();
  if (threadIdx.x == 0) {
    atomicAdd(&accbuf[0], rs[0] + rs[1] + rs[2] + rs[3]);
    atomicAdd(&accbuf[1], rc[0] + rc[1] + rc[2] + rc[3]);
  }
}

__global__ void final_div_kernel(const float* __restrict__ accbuf, float* __restrict__ out) {
  out[0] = accbuf[0] / fmaxf(accbuf[1], 1.f);
}

extern "C" void kernel_launch(void* const* d_in, const int* in_sizes, int n_in,
                              void* d_out, int out_size, void* d_ws, size_t ws_size,
                              hipStream_t stream) {
  const float* h   = (const float*)d_in[0];   // (4, 2048, 2048) fp32
  const float* wgt = (const float*)d_in[1];   // (32000, 2048) fp32
  const int* labels = (const int*)d_in[2];    // (4, 2048) int32
  float* out = (float*)d_out;

  // workspace layout (bytes)
  char* ws = (char*)d_ws;
  ushort_t* wb   = (ushort_t*)(ws);                               // 131,072,000
  ushort_t* hb   = (ushort_t*)(ws + 131072000);                   //  33,554,432
  float*    pmax = (float*)(ws + 131072000 + 33554432);           //  16,384,000
  float*    psum = (float*)(ws + 131072000 + 33554432 + 16384000);//  16,384,000
  float*    zl   = (float*)(ws + 131072000 + 33554432 + 2*16384000);          // 32,768
  float*    accbuf = (float*)(ws + 131072000 + 33554432 + 2*16384000 + 32768);// 8

  conv_h_kernel<<<2048, 256, 0, stream>>>(h, hb, accbuf);
  conv_w_kernel<<<4096, 256, 0, stream>>>(wgt, wb);
  zlabel_kernel<<<N_, 256, 0, stream>>>(h, wgt, labels, zl);
  gemm_lse_kernel<<<dim3(V_ / TILE_N, Npad / TILE_M), 256, 0, stream>>>(hb, wb, pmax, psum);
  finalize_kernel<<<Npad / 256, 256, 0, stream>>>(pmax, psum, zl, labels, accbuf);
  final_div_kernel<<<1, 1, 0, stream>>>(accbuf, out);
}